// Round 7
// baseline (1523.248 us; speedup 1.0000x reference)
//
#include <hip/hip_runtime.h>
#include <cstdint>
#include <cstddef>

#define GN   16384
#define GIN  128
#define GOUT 64
#define NCH  8          // column chunks (width 2048)
#define LOG2E 1.44269504088896340736f

typedef __attribute__((ext_vector_type(8))) short short8;
typedef __attribute__((ext_vector_type(4))) float f32x4;
typedef __attribute__((ext_vector_type(4))) int   int4v;

__device__ __forceinline__ unsigned short f2bf_rne(float f) {
  unsigned u = __float_as_uint(f);
  u += 0x7FFFu + ((u >> 16) & 1u);
  return (unsigned short)(u >> 16);
}

// ---------------------------------------------------------------------------
// mask: adj (int32, 1.07 GB) -> byte mask (33.5 MB), fully sequential stream.
//   msk[b] bit t = (adj[b*8 + t] != 0)
// ---------------------------------------------------------------------------
__global__ __launch_bounds__(256) void mask_kernel(
    const int* __restrict__ adj, unsigned char* __restrict__ msk)
{
  const unsigned nb = (unsigned)((size_t)GN * (size_t)GN / 8);  // 33,554,432
  const unsigned stride = gridDim.x * 256;
  for (unsigned b = blockIdx.x * 256 + threadIdx.x; b < nb; b += stride) {
    const int4v* p = (const int4v*)(adj + (size_t)b * 8);
    int4v x0 = __builtin_nontemporal_load(p);
    int4v x1 = __builtin_nontemporal_load(p + 1);
    unsigned by = (unsigned)(x0.x != 0)
                | ((unsigned)(x0.y != 0) << 1)
                | ((unsigned)(x0.z != 0) << 2)
                | ((unsigned)(x0.w != 0) << 3)
                | ((unsigned)(x1.x != 0) << 4)
                | ((unsigned)(x1.y != 0) << 5)
                | ((unsigned)(x1.z != 0) << 6)
                | ((unsigned)(x1.w != 0) << 7);
    msk[b] = (unsigned char)by;                  // regular store: stays in L2/L3
  }
}

// ---------------------------------------------------------------------------
// prep: Wh = x@W, f_src/f_dst (x log2e), Wh packed in MFMA B-fragment order.
// v12 additions (per-row, O(N) work): c0 = 2^fs2, c1 = 2^(0.02*fs2) f32;
// ddpk = packed bf16 pair {lo: 2^fd2 (s>=0 branch), hi: 2^(0.02*fd2) (s<0)}.
// wpk TRUE footprint = 512 tiles * 4096 ushorts = 4 MB.
// ---------------------------------------------------------------------------
__global__ __launch_bounds__(256) void prep_kernel(
    const float* __restrict__ x, const float* __restrict__ w,
    const float* __restrict__ aw, unsigned short* __restrict__ wpk,
    float* __restrict__ fs2, float* __restrict__ fd2,
    float* __restrict__ c0, float* __restrict__ c1,
    unsigned* __restrict__ ddpk)
{
  __shared__ float ws[GIN * GOUT];          // 32 KB
  __shared__ float red[2][64][4];

  const int t = threadIdx.x;
  const int rb = blockIdx.x * 64;

  for (int i = t; i < (GIN * GOUT) / 4; i += 256)
    ((float4*)ws)[i] = ((const float4*)w)[i];
  __syncthreads();

  const int r = t & 63, s = t >> 6;
  const int row = rb + r;
  const float* xr = x + (size_t)row * GIN;

  float acc[16];
#pragma unroll
  for (int d = 0; d < 16; ++d) acc[d] = 0.f;

  for (int kk = 0; kk < GIN; kk += 4) {
    float4 xv = *(const float4*)(xr + kk);
    float xa[4] = {xv.x, xv.y, xv.z, xv.w};
#pragma unroll
    for (int u = 0; u < 4; ++u) {
#pragma unroll
      for (int d = 0; d < 16; ++d)
        acc[d] += xa[u] * ws[(kk + u) * GOUT + s * 16 + d];
    }
  }

  const int jc = row >> 5;
  const int qq = (row & 31) >> 3;
  const int tt = row & 7;
  float psrc = 0.f, pdst = 0.f;
#pragma unroll
  for (int d = 0; d < 16; ++d) {
    const int dg = s * 16 + d;
    psrc += acc[d] * aw[dg];
    pdst += acc[d] * aw[GOUT + dg];
    const int f = dg >> 4, n = dg & 15;
    wpk[(size_t)jc * 4096 + f * 1024 + (qq * 16 + n) * 8 + tt] = f2bf_rne(acc[d]);
  }
  red[0][r][s] = psrc;
  red[1][r][s] = pdst;
  __syncthreads();
  if (s == 0) {
    float a_ = red[0][r][0] + red[0][r][1] + red[0][r][2] + red[0][r][3];
    float b_ = red[1][r][0] + red[1][r][1] + red[1][r][2] + red[1][r][3];
    float fsv = a_ * LOG2E;
    float fdv = b_ * LOG2E;
    fs2[row] = fsv;
    fd2[row] = fdv;
    c0[row] = exp2f(fsv);            // row factor, s>=0 branch
    c1[row] = exp2f(0.02f * fsv);    // row factor, s<0 branch
    float d0 = exp2f(fdv);           // col factor, s>=0 branch
    float d1 = exp2f(0.02f * fdv);   // col factor, s<0 branch
    ddpk[row] = (unsigned)f2bf_rne(d0) | ((unsigned)f2bf_rne(d1) << 16);
  }
}

// ---------------------------------------------------------------------------
// main v12: branch-factorized score path — NO exp2 / f2bf / float math in the
// inner loop. exp2(lrelu(fs+fd)) = (s>=0) ? 2^fs*2^fd : 2^{.02fs}*2^{.02fd}.
// A-fragment carries the bf16 col factor selected by (adj bit) & (sign test);
// two accumulator sets (plus/minus branch), row factors c0/c1 applied in f32
// epilogue. num & den share the same af values -> correlated rounding as v7.
// Per element: 1 cmp + 2 cndmask + 2 and (~7 ops) vs ~13 incl quarter-rate
// exp2 before. MFMA 10->20 per step (separate pipe, ~idle before).
// ---------------------------------------------------------------------------
__global__ __launch_bounds__(256, 2) void gat_main(
    const unsigned* __restrict__ bmw, const unsigned short* __restrict__ wpk,
    const float* __restrict__ fs2, const float* __restrict__ fd2,
    const float* __restrict__ c0, const float* __restrict__ c1,
    const unsigned* __restrict__ ddpk,
    float* __restrict__ nump, float* __restrict__ denp)
{
  const int wave  = blockIdx.x * 4 + (threadIdx.x >> 6);
  const int lane  = threadIdx.x & 63;
  const int strip = wave & 511;             // 512 strips of 32 rows
  const int chunk = wave >> 9;              // 8 column chunks
  const int m = lane & 15;
  const int q = lane >> 4;
  const int q8 = q << 3;

  const int row0 = strip * 32 + m;          // group 0 row
  const int row1 = row0 + 16;               // group 1 row
  const float nf0 = -fs2[row0];             // cmp threshold: fd >= -fs
  const float nf1 = -fs2[row1];
  const unsigned* __restrict__ bmr0 = bmw + (size_t)row0 * (GN / 32);
  const unsigned* __restrict__ bmr1 = bmw + (size_t)row1 * (GN / 32);

  const int CW = GN / NCH;                  // 2048 columns per chunk
  const int j0 = chunk * CW;
  const float4* __restrict__ fdv  = (const float4*)fd2;
  const int4v*  __restrict__ ddv  = (const int4v*)ddpk;
  const short8* __restrict__ wpk8 = (const short8*)wpk;

  f32x4 accP0[4], accM0[4], accP1[4], accM1[4];
  f32x4 accPd0, accMd0, accPd1, accMd1;
  accPd0 = accMd0 = accPd1 = accMd1 = (f32x4){0.f, 0.f, 0.f, 0.f};
#pragma unroll
  for (int b = 0; b < 4; ++b) {
    accP0[b] = accM0[b] = accP1[b] = accM1[b] = (f32x4){0.f, 0.f, 0.f, 0.f};
  }

  short8 b_ones;
#pragma unroll
  for (int i = 0; i < 8; ++i) b_ones[i] = (short)0x3F80;  // bf16 1.0

  // per element t: afp = adjbit & (fd>=nf) ? bf16(d) : 0
  //                afm = adjbit & (fd< nf) ? bf16(d') : 0
  auto mk2 = [&](unsigned byte, float4 fA, float4 fB, int4v dA, int4v dB,
                 float nf, short8& afp, short8& afm) {
    float fe[8] = {fA.x, fA.y, fA.z, fA.w, fB.x, fB.y, fB.z, fB.w};
    unsigned de[8] = {(unsigned)dA.x, (unsigned)dA.y, (unsigned)dA.z, (unsigned)dA.w,
                      (unsigned)dB.x, (unsigned)dB.y, (unsigned)dB.z, (unsigned)dB.w};
#pragma unroll
    for (int t = 0; t < 8; ++t) {
      const bool cm = (fe[t] >= nf);
      const unsigned bmask = (unsigned)(-(int)((byte >> t) & 1u));  // 0 / ~0
      const unsigned lo = cm ? (de[t] & 0xffffu) : 0u;
      const unsigned hi = cm ? 0u : (de[t] >> 16);
      afp[t] = (short)(lo & bmask);
      afm[t] = (short)(hi & bmask);
    }
  };

#pragma unroll 1
  for (int j = j0; j < j0 + CW; j += 32) {
    const int i4 = (j >> 2) + (q << 1);
    const int wi = j >> 5;

    const unsigned w0 = bmr0[wi];
    const unsigned w1 = bmr1[wi];
    const float4 f0 = fdv[i4];
    const float4 f1 = fdv[i4 + 1];
    const int4v d0 = ddv[i4];
    const int4v d1 = ddv[i4 + 1];

    // packed B fragments: 4 contiguous 1 KB wave-loads, shared by both groups
    const short8* wb = wpk8 + (size_t)wi * 512 + lane;
    const short8 b0 = wb[0];
    const short8 b1 = wb[128];
    const short8 b2 = wb[256];
    const short8 b3 = wb[384];

    {
      short8 afp, afm;
      mk2((w0 >> q8) & 0xffu, f0, f1, d0, d1, nf0, afp, afm);
      accP0[0] = __builtin_amdgcn_mfma_f32_16x16x32_bf16(afp, b0, accP0[0], 0, 0, 0);
      accP0[1] = __builtin_amdgcn_mfma_f32_16x16x32_bf16(afp, b1, accP0[1], 0, 0, 0);
      accP0[2] = __builtin_amdgcn_mfma_f32_16x16x32_bf16(afp, b2, accP0[2], 0, 0, 0);
      accP0[3] = __builtin_amdgcn_mfma_f32_16x16x32_bf16(afp, b3, accP0[3], 0, 0, 0);
      accPd0   = __builtin_amdgcn_mfma_f32_16x16x32_bf16(afp, b_ones, accPd0, 0, 0, 0);
      accM0[0] = __builtin_amdgcn_mfma_f32_16x16x32_bf16(afm, b0, accM0[0], 0, 0, 0);
      accM0[1] = __builtin_amdgcn_mfma_f32_16x16x32_bf16(afm, b1, accM0[1], 0, 0, 0);
      accM0[2] = __builtin_amdgcn_mfma_f32_16x16x32_bf16(afm, b2, accM0[2], 0, 0, 0);
      accM0[3] = __builtin_amdgcn_mfma_f32_16x16x32_bf16(afm, b3, accM0[3], 0, 0, 0);
      accMd0   = __builtin_amdgcn_mfma_f32_16x16x32_bf16(afm, b_ones, accMd0, 0, 0, 0);
    }
    {
      short8 afp, afm;
      mk2((w1 >> q8) & 0xffu, f0, f1, d0, d1, nf1, afp, afm);
      accP1[0] = __builtin_amdgcn_mfma_f32_16x16x32_bf16(afp, b0, accP1[0], 0, 0, 0);
      accP1[1] = __builtin_amdgcn_mfma_f32_16x16x32_bf16(afp, b1, accP1[1], 0, 0, 0);
      accP1[2] = __builtin_amdgcn_mfma_f32_16x16x32_bf16(afp, b2, accP1[2], 0, 0, 0);
      accP1[3] = __builtin_amdgcn_mfma_f32_16x16x32_bf16(afp, b3, accP1[3], 0, 0, 0);
      accPd1   = __builtin_amdgcn_mfma_f32_16x16x32_bf16(afp, b_ones, accPd1, 0, 0, 0);
      accM1[0] = __builtin_amdgcn_mfma_f32_16x16x32_bf16(afm, b0, accM1[0], 0, 0, 0);
      accM1[1] = __builtin_amdgcn_mfma_f32_16x16x32_bf16(afm, b1, accM1[1], 0, 0, 0);
      accM1[2] = __builtin_amdgcn_mfma_f32_16x16x32_bf16(afm, b2, accM1[2], 0, 0, 0);
      accM1[3] = __builtin_amdgcn_mfma_f32_16x16x32_bf16(afm, b3, accM1[3], 0, 0, 0);
      accMd1   = __builtin_amdgcn_mfma_f32_16x16x32_bf16(afm, b_ones, accMd1, 0, 0, 0);
    }
  }

  // epilogue: num = c0*accP + c1*accM (f32), plain stores to private slab
  float* np = nump + (size_t)chunk * GN * GOUT;
  float* dp = denp + (size_t)chunk * GN;
  {
    const int orow0 = strip * 32 + q * 4;            // group 0: C/D row=q*4+r, col=m
#pragma unroll
    for (int r = 0; r < 4; ++r) {
      const float cp = c0[orow0 + r];
      const float cm_ = c1[orow0 + r];
      float* nr = np + (size_t)(orow0 + r) * GOUT + m;
      __builtin_nontemporal_store(cp * accP0[0][r] + cm_ * accM0[0][r], nr + 0);
      __builtin_nontemporal_store(cp * accP0[1][r] + cm_ * accM0[1][r], nr + 16);
      __builtin_nontemporal_store(cp * accP0[2][r] + cm_ * accM0[2][r], nr + 32);
      __builtin_nontemporal_store(cp * accP0[3][r] + cm_ * accM0[3][r], nr + 48);
      if (m == 0) dp[orow0 + r] = cp * accPd0[r] + cm_ * accMd0[r];
    }
  }
  {
    const int orow0 = strip * 32 + 16 + q * 4;       // group 1
#pragma unroll
    for (int r = 0; r < 4; ++r) {
      const float cp = c0[orow0 + r];
      const float cm_ = c1[orow0 + r];
      float* nr = np + (size_t)(orow0 + r) * GOUT + m;
      __builtin_nontemporal_store(cp * accP1[0][r] + cm_ * accM1[0][r], nr + 0);
      __builtin_nontemporal_store(cp * accP1[1][r] + cm_ * accM1[1][r], nr + 16);
      __builtin_nontemporal_store(cp * accP1[2][r] + cm_ * accM1[2][r], nr + 32);
      __builtin_nontemporal_store(cp * accP1[3][r] + cm_ * accM1[3][r], nr + 48);
      if (m == 0) dp[orow0 + r] = cp * accPd1[r] + cm_ * accMd1[r];
    }
  }
}

// ---------------------------------------------------------------------------
// finalize: out = elu( (sum_c num_c) / (sum_c den_c) )
// ---------------------------------------------------------------------------
__global__ __launch_bounds__(256) void fin_kernel(
    const float* __restrict__ nump, const float* __restrict__ denp,
    float* __restrict__ out)
{
  const int g = blockIdx.x * 256 + threadIdx.x;
  if (g >= GN * GOUT) return;
  const int row = g >> 6;
  float s = 0.f, d = 0.f;
#pragma unroll
  for (int c = 0; c < NCH; ++c) {
    s += nump[(size_t)c * GN * GOUT + g];
    d += denp[(size_t)c * GN + row];
  }
  float v = s / d;
  out[g] = (v > 0.f) ? v : expm1f(v);
}

extern "C" void kernel_launch(void* const* d_in, const int* in_sizes, int n_in,
                              void* d_out, int out_size, void* d_ws, size_t ws_size,
                              hipStream_t stream) {
  const float* x   = (const float*)d_in[0];
  const int*   adj = (const int*)d_in[1];
  const float* w   = (const float*)d_in[2];
  const float* aw  = (const float*)d_in[3];
  float* out = (float*)d_out;

  // ws layout (floats): nump[8*N*64] | denp[8*N] | fs2[N] | fd2[N] | c0[N] |
  //   c1[N] | ddpk[N u32] | wpk (512 tiles x 4096 ushorts = 4 MB TRUE extent) |
  //   msk (N*N/8 bytes, 33.5 MB)
  float* nump = (float*)d_ws;
  float* denp = nump + (size_t)NCH * GN * GOUT;
  float* fs2  = denp + (size_t)NCH * GN;
  float* fd2  = fs2 + GN;
  float* c0   = fd2 + GN;
  float* c1   = c0 + GN;
  unsigned* ddpk = (unsigned*)(c1 + GN);
  unsigned short* wpk = (unsigned short*)(ddpk + GN);
  // wpk spans 512*4096 ushorts (tile stride 4096, half-used frag slots) = 4 MB.
  unsigned char* msk = (unsigned char*)(wpk + (size_t)512 * 4096);
  // ~72 MB of the ws; everything fully written before read -> no memset needed

  mask_kernel<<<2048, 256, 0, stream>>>(adj, msk);
  prep_kernel<<<GN / 64, 256, 0, stream>>>(x, w, aw, wpk, fs2, fd2, c0, c1, ddpk);
  gat_main<<<(GN / 32) * NCH / 4, 256, 0, stream>>>((const unsigned*)msk, wpk,
                                                    fs2, fd2, c0, c1, ddpk, nump, denp);
  fin_kernel<<<(GN * GOUT) / 256, 256, 0, stream>>>(nump, denp, out);
}

// Round 8
// 1398.074 us; speedup vs baseline: 1.0895x; 1.0895x over previous
//
#include <hip/hip_runtime.h>
#include <cstdint>
#include <cstddef>

#define GN   16384
#define GIN  128
#define GOUT 64
#define NCH  8          // column chunks (width 2048)
#define LOG2E 1.44269504088896340736f

typedef __attribute__((ext_vector_type(8))) short short8;
typedef __attribute__((ext_vector_type(4))) float f32x4;
typedef __attribute__((ext_vector_type(4))) int   int4v;

__device__ __forceinline__ unsigned short f2bf(float f) {
  unsigned u = __float_as_uint(f);
  return (unsigned short)((u + 0x8000u) >> 16);   // round-half-up (cheap)
}

__device__ __forceinline__ unsigned short f2bf_rne(float f) {
  unsigned u = __float_as_uint(f);
  u += 0x7FFFu + ((u >> 16) & 1u);
  return (unsigned short)(u >> 16);
}

// ---------------------------------------------------------------------------
// prep (verified): Wh = x@W, f_src/f_dst (x log2e), Wh packed in MFMA
// B-fragment order: wpk[col_tile(512)][frag(4)][lane(64)][t(8)] bf16.
// wpk TRUE footprint = 512 tiles * 4096 ushorts = 4 MB.
// ---------------------------------------------------------------------------
__global__ __launch_bounds__(256) void prep_kernel(
    const float* __restrict__ x, const float* __restrict__ w,
    const float* __restrict__ aw, unsigned short* __restrict__ wpk,
    float* __restrict__ fs2, float* __restrict__ fd2)
{
  __shared__ float ws[GIN * GOUT];          // 32 KB
  __shared__ float red[2][64][4];

  const int t = threadIdx.x;
  const int rb = blockIdx.x * 64;

  for (int i = t; i < (GIN * GOUT) / 4; i += 256)
    ((float4*)ws)[i] = ((const float4*)w)[i];
  __syncthreads();

  const int r = t & 63, s = t >> 6;
  const int row = rb + r;
  const float* xr = x + (size_t)row * GIN;

  float acc[16];
#pragma unroll
  for (int d = 0; d < 16; ++d) acc[d] = 0.f;

  for (int kk = 0; kk < GIN; kk += 4) {
    float4 xv = *(const float4*)(xr + kk);
    float xa[4] = {xv.x, xv.y, xv.z, xv.w};
#pragma unroll
    for (int u = 0; u < 4; ++u) {
#pragma unroll
      for (int d = 0; d < 16; ++d)
        acc[d] += xa[u] * ws[(kk + u) * GOUT + s * 16 + d];
    }
  }

  const int jc = row >> 5;
  const int qq = (row & 31) >> 3;
  const int tt = row & 7;
  float psrc = 0.f, pdst = 0.f;
#pragma unroll
  for (int d = 0; d < 16; ++d) {
    const int dg = s * 16 + d;
    psrc += acc[d] * aw[dg];
    pdst += acc[d] * aw[GOUT + dg];
    const int f = dg >> 4, n = dg & 15;
    wpk[(size_t)jc * 4096 + f * 1024 + (qq * 16 + n) * 8 + tt] = f2bf_rne(acc[d]);
  }
  red[0][r][s] = psrc;
  red[1][r][s] = pdst;
  __syncthreads();
  if (s == 0) {
    float a_ = red[0][r][0] + red[0][r][1] + red[0][r][2] + red[0][r][3];
    float b_ = red[1][r][0] + red[1][r][1] + red[1][r][2] + red[1][r][3];
    fs2[row] = a_ * LOG2E;
    fd2[row] = b_ * LOG2E;
  }
}

// ---------------------------------------------------------------------------
// main v13: FUSED adjacency. No separate mask kernel / no msk buffer.
// Per block (256 thr = 4 waves): 128 rows x one 2048-col chunk.
// Phase A: each wave stages its own 32 rows of adj -> LDS bitmask,
//   reading adj ROW-LINEARLY (8 KB contiguous per row = good DRAM pages,
//   vs v7's 128 B-per-64KB-stride visits). lane covers cols [lane*32,+32)
//   of each row -> one u32, ds_write conflict-free.
// Phase B: verified v10/v11 sweep (pelem exp2 + f2bf numeric path),
//   mask words from LDS (row stride 66 words -> 16 distinct banks).
// ---------------------------------------------------------------------------
__global__ __launch_bounds__(256, 2) void gat_main(
    const int* __restrict__ adj, const unsigned short* __restrict__ wpk,
    const float* __restrict__ fs2, const float* __restrict__ fd2,
    float* __restrict__ nump, float* __restrict__ denp)
{
  __shared__ unsigned mk[4][32][66];        // 33.8 KB

  const int w    = threadIdx.x >> 6;        // wave in block
  const int lane = threadIdx.x & 63;
  const int br    = blockIdx.x & 127;       // 128 row-blocks of 128 rows
  const int chunk = blockIdx.x >> 7;        // 8 column chunks
  const int strip32 = br * 4 + w;           // global 32-row strip of this wave
  const int m = lane & 15;
  const int q = lane >> 4;
  const int q8 = q << 3;

  const int CW = GN / NCH;                  // 2048 columns per chunk
  const int j0 = chunk * CW;

  // ---- Phase A: stage this wave's 32 rows of adj into LDS bitmask ----
  {
    const int4v* ap = (const int4v*)(adj + (size_t)(strip32 * 32) * GN + j0);
    const int lane8 = lane * 8;             // int4 index of this lane's 32 cols
#pragma unroll 1
    for (int r = 0; r < 32; ++r) {
      unsigned bits = 0;
#pragma unroll
      for (int k = 0; k < 8; ++k) {
        int4v v = ap[lane8 + k];
        bits |= ((unsigned)(v.x != 0) << (k * 4))
              | ((unsigned)(v.y != 0) << (k * 4 + 1))
              | ((unsigned)(v.z != 0) << (k * 4 + 2))
              | ((unsigned)(v.w != 0) << (k * 4 + 3));
      }
      mk[w][r][lane] = bits;
      ap += GN / 4;                         // next row (GN ints = GN/4 int4)
    }
  }
  __syncthreads();

  // ---- Phase B: verified sweep (v10 numeric path, 2 row groups) ----
  const int row0 = strip32 * 32 + m;
  const int row1 = row0 + 16;
  const float fs0 = fs2[row0];
  const float fs1 = fs2[row1];

  const float4* __restrict__ fdv  = (const float4*)fd2;
  const short8* __restrict__ wpk8 = (const short8*)wpk;

  f32x4 acc0[4], acc1[4];
  f32x4 accd0, accd1;
  accd0 = accd1 = (f32x4){0.f, 0.f, 0.f, 0.f};
#pragma unroll
  for (int b = 0; b < 4; ++b) {
    acc0[b] = (f32x4){0.f, 0.f, 0.f, 0.f};
    acc1[b] = (f32x4){0.f, 0.f, 0.f, 0.f};
  }

  short8 b_ones;
#pragma unroll
  for (int i = 0; i < 8; ++i) b_ones[i] = (short)0x3F80;  // bf16 1.0

  auto pelem = [&](unsigned byte, int t, float fd, float fsv) -> unsigned short {
    float sv = fsv + fd;
    float lv = fmaxf(sv, 0.02f * sv);       // lrelu (commutes with *log2e)
    float pe = __builtin_amdgcn_exp2f(lv);
    pe = (byte & (1u << t)) ? pe : 0.f;
    return f2bf(pe);
  };

  auto mk_af = [&](unsigned byte, float4 fA, float4 fB, float fsv) -> short8 {
    short8 af;
    af[0] = (short)pelem(byte, 0, fA.x, fsv);
    af[1] = (short)pelem(byte, 1, fA.y, fsv);
    af[2] = (short)pelem(byte, 2, fA.z, fsv);
    af[3] = (short)pelem(byte, 3, fA.w, fsv);
    af[4] = (short)pelem(byte, 4, fB.x, fsv);
    af[5] = (short)pelem(byte, 5, fB.y, fsv);
    af[6] = (short)pelem(byte, 6, fB.z, fsv);
    af[7] = (short)pelem(byte, 7, fB.w, fsv);
    return af;
  };

#pragma unroll 1
  for (int j = j0; j < j0 + CW; j += 32) {
    const int i4 = (j >> 2) + (q << 1);
    const int wi = (j - j0) >> 5;           // chunk-local mask word index

    const unsigned w0 = mk[w][m][wi];       // 16 banks, q-broadcast: conflict-free
    const unsigned w1 = mk[w][m + 16][wi];
    const float4 f0 = fdv[i4];
    const float4 f1 = fdv[i4 + 1];

    // packed B fragments: 4 contiguous 1 KB wave-loads, shared by both groups
    const short8* wb = wpk8 + (size_t)(j >> 5) * 512 + lane;
    const short8 b0 = wb[0];
    const short8 b1 = wb[128];
    const short8 b2 = wb[256];
    const short8 b3 = wb[384];

    {
      const unsigned byte = (w0 >> q8) & 0xffu;
      short8 af = mk_af(byte, f0, f1, fs0);
      acc0[0] = __builtin_amdgcn_mfma_f32_16x16x32_bf16(af, b0, acc0[0], 0, 0, 0);
      acc0[1] = __builtin_amdgcn_mfma_f32_16x16x32_bf16(af, b1, acc0[1], 0, 0, 0);
      acc0[2] = __builtin_amdgcn_mfma_f32_16x16x32_bf16(af, b2, acc0[2], 0, 0, 0);
      acc0[3] = __builtin_amdgcn_mfma_f32_16x16x32_bf16(af, b3, acc0[3], 0, 0, 0);
      accd0   = __builtin_amdgcn_mfma_f32_16x16x32_bf16(af, b_ones, accd0, 0, 0, 0);
    }
    {
      const unsigned byte = (w1 >> q8) & 0xffu;
      short8 af = mk_af(byte, f0, f1, fs1);
      acc1[0] = __builtin_amdgcn_mfma_f32_16x16x32_bf16(af, b0, acc1[0], 0, 0, 0);
      acc1[1] = __builtin_amdgcn_mfma_f32_16x16x32_bf16(af, b1, acc1[1], 0, 0, 0);
      acc1[2] = __builtin_amdgcn_mfma_f32_16x16x32_bf16(af, b2, acc1[2], 0, 0, 0);
      acc1[3] = __builtin_amdgcn_mfma_f32_16x16x32_bf16(af, b3, acc1[3], 0, 0, 0);
      accd1   = __builtin_amdgcn_mfma_f32_16x16x32_bf16(af, b_ones, accd1, 0, 0, 0);
    }
  }

  // epilogue: plain stores into this chunk's private slab (no atomics)
  float* np = nump + (size_t)chunk * GN * GOUT;
  float* dp = denp + (size_t)chunk * GN;
  {
    const int orow0 = strip32 * 32 + q * 4;          // group 0: C/D row=q*4+r, col=m
#pragma unroll
    for (int r = 0; r < 4; ++r) {
      float* nr = np + (size_t)(orow0 + r) * GOUT + m;
      __builtin_nontemporal_store(acc0[0][r], nr + 0);
      __builtin_nontemporal_store(acc0[1][r], nr + 16);
      __builtin_nontemporal_store(acc0[2][r], nr + 32);
      __builtin_nontemporal_store(acc0[3][r], nr + 48);
      if (m == 0) dp[orow0 + r] = accd0[r];
    }
  }
  {
    const int orow0 = strip32 * 32 + 16 + q * 4;     // group 1
#pragma unroll
    for (int r = 0; r < 4; ++r) {
      float* nr = np + (size_t)(orow0 + r) * GOUT + m;
      __builtin_nontemporal_store(acc1[0][r], nr + 0);
      __builtin_nontemporal_store(acc1[1][r], nr + 16);
      __builtin_nontemporal_store(acc1[2][r], nr + 32);
      __builtin_nontemporal_store(acc1[3][r], nr + 48);
      if (m == 0) dp[orow0 + r] = accd1[r];
    }
  }
}

// ---------------------------------------------------------------------------
// finalize: out = elu( (sum_c num_c) / (sum_c den_c) )
// ---------------------------------------------------------------------------
__global__ __launch_bounds__(256) void fin_kernel(
    const float* __restrict__ nump, const float* __restrict__ denp,
    float* __restrict__ out)
{
  const int g = blockIdx.x * 256 + threadIdx.x;
  if (g >= GN * GOUT) return;
  const int row = g >> 6;
  float s = 0.f, d = 0.f;
#pragma unroll
  for (int c = 0; c < NCH; ++c) {
    s += nump[(size_t)c * GN * GOUT + g];
    d += denp[(size_t)c * GN + row];
  }
  float v = s / d;
  out[g] = (v > 0.f) ? v : expm1f(v);
}

extern "C" void kernel_launch(void* const* d_in, const int* in_sizes, int n_in,
                              void* d_out, int out_size, void* d_ws, size_t ws_size,
                              hipStream_t stream) {
  const float* x   = (const float*)d_in[0];
  const int*   adj = (const int*)d_in[1];
  const float* w   = (const float*)d_in[2];
  const float* aw  = (const float*)d_in[3];
  float* out = (float*)d_out;

  // ws layout (floats): nump[8*N*64] | denp[8*N] | fs2[N] | fd2[N] |
  //                     wpk (512 tiles x 4096 ushorts = 4 MB TRUE extent)
  float* nump = (float*)d_ws;
  float* denp = nump + (size_t)NCH * GN * GOUT;
  float* fs2  = denp + (size_t)NCH * GN;
  float* fd2  = fs2 + GN;
  unsigned short* wpk = (unsigned short*)(fd2 + GN);
  // ~38.5 MB of the ws; everything fully written before read -> no memset needed

  prep_kernel<<<GN / 64, 256, 0, stream>>>(x, w, aw, wpk, fs2, fd2);
  gat_main<<<(GN / 128) * NCH, 256, 0, stream>>>(adj, wpk, fs2, fd2, nump, denp);
  fin_kernel<<<(GN * GOUT) / 256, 256, 0, stream>>>(nump, denp, out);
}